// Round 12
// baseline (476.535 us; speedup 1.0000x reference)
//
#include <hip/hip_runtime.h>
#include <hip/hip_bf16.h>

// NARX RNN. Inputs fp32, compute bf16 MFMA 16x16x32, output fp32.
// ZERO-LDS-hot-loop via K-permuted weights (validated R11):
//   C/D layout: lane (m=lane&15, q=lane>>4) holds rows 16tn+4q+r. Packing
//   pairs in natural order and consuming u32x4 groups as B-frags places unit
//   32kk+psi(q,j) at K-position 32kk+8q+j; staging Wxh^T/Whh^T with K
//   permuted by pi(p)=32(p>>5)+16((p>>2)&1)+4((p>>3)&3)+(p&3) matches A to B
//   exactly -> C->B transform is a register renaming.
// R12 changes (R11 post-mortem: 41MB scratch spill + 30% occupancy cap):
//   - u-ring DROPPED: recompute u inline per (ti,d) (2.3x u redundancy) to
//     free 32 regs -> fits __launch_bounds__(256,4) = 4 blocks/CU.
//   - b_in / b_h(scaled) / W_out live in small LDS arrays, reloaded per step:
//     RA rematerializes from LDS instead of scratch-spilling.
//   - TTB 4->8 (runtime tail) halves per-block weight staging; grid 32x64.
// tanh has 2*log2(e) folded into Wxh/Whh/bh (exp2-based, no mul).

#define NG    2048
#define NXF   16
#define HIDN  64
#define DLAG  4
#define TOUTN 508
#define GBLK  64    // g rows per block (4 waves x 16)
#define TTB   8     // tt values per block (last y-block does 4)
#define STR   72    // staging stride (shorts)
#define SW    32    // resident Win^T stride (shorts)
#define SCALE 2.8853900817779268f   // 2*log2(e)

typedef short  s16x8 __attribute__((ext_vector_type(8)));
typedef float  f32x4 __attribute__((ext_vector_type(4)));
typedef unsigned int u32x4 __attribute__((ext_vector_type(4)));

__device__ __forceinline__ unsigned short f2bf(float f) {  // RTNE (init only)
    unsigned int u = __float_as_uint(f);
    u += 0x7fffu + ((u >> 16) & 1u);
    return (unsigned short)(u >> 16);
}
__device__ __forceinline__ unsigned int pk2bf(float a, float b) {  // [lo=a, hi=b]
    union { __hip_bfloat162 h2; unsigned int u; } c;
    c.h2 = __float22bfloat162_rn(float2{a, b});
    return c.u;
}
__device__ __forceinline__ float tanh_pre(float a) {
    // a is already scaled by 2*log2(e) (folded into weights/bias)
    float e = exp2f(a);
    return fmaf(-2.0f, __builtin_amdgcn_rcpf(e + 1.0f), 1.0f);
}

__global__ __launch_bounds__(256, 4)
void narx_kernel(const float* __restrict__ x,
                 const float* __restrict__ Win,
                 const float* __restrict__ bin_g,
                 const float* __restrict__ Wxh,
                 const float* __restrict__ Whh,
                 const float* __restrict__ bh_g,
                 const float* __restrict__ Wout,
                 const float* __restrict__ bout_g,
                 float* __restrict__ out)
{
    __shared__ unsigned short s_stage[HIDN * STR];  // transient weight staging
    __shared__ unsigned short s_win[HIDN * SW];     // resident Win^T, pad zeroed
    __shared__ float s_bin[HIDN];                   // b_in (fp32)
    __shared__ float s_bh[HIDN];                    // b_h * SCALE (fp32)
    __shared__ float s_wout[HIDN];                  // W_out (fp32)

    const int tid   = threadIdx.x;
    const int lane  = tid & 63;
    const int lm    = lane & 15;
    const int q     = lane >> 4;
    const int G0    = blockIdx.x * GBLK;
    const int tt0   = blockIdx.y * TTB;
    const int wrow0 = (tid >> 6) * 16;
    const int myg   = G0 + wrow0 + lm;

    int nti = TOUTN - tt0;
    if (nti > TTB) nti = TTB;

    // zero the t<DLAG head of the output (poisoned before every launch)
    if (blockIdx.y == 0 && tid < GBLK) {
        #pragma unroll
        for (int t2 = 0; t2 < DLAG; ++t2)
            out[t2 * NG + G0 + tid] = 0.0f;
    }

    // zero s_win pad slots 16..31 (disjoint from data slots 0..15: no race)
    {
        int r = tid >> 2, c0 = 16 + (tid & 3) * 4;
        #pragma unroll
        for (int i = 0; i < 4; ++i) s_win[r * SW + c0 + i] = 0;
    }

    // ---- stage Wxh^T / Whh^T with K permuted by pi, scaled; frags to regs ----
    const int p0  = tid >> 2;              // K-position this thread stages
    const int pi0 = 32*(p0>>5) + 16*((p0>>2)&1) + 4*((p0>>3)&3) + (p0&3);
    const int n0  = (tid & 3) * 16;

    s16x8 wxhf[4][2], whhf[4][2];
    {
        const float* src = Wxh + pi0 * HIDN + n0;
        #pragma unroll
        for (int i = 0; i < 16; ++i)
            s_stage[(n0 + i) * STR + p0] = f2bf(src[i] * SCALE);
    }
    __syncthreads();
    #pragma unroll
    for (int tn = 0; tn < 4; ++tn)
        #pragma unroll
        for (int kk = 0; kk < 2; ++kk)
            wxhf[tn][kk] = *(const s16x8*)&s_stage[(tn*16 + lm) * STR + kk*32 + q*8];
    __syncthreads();
    {
        const float* src = Whh + pi0 * HIDN + n0;
        #pragma unroll
        for (int i = 0; i < 16; ++i)
            s_stage[(n0 + i) * STR + p0] = f2bf(src[i] * SCALE);
    }
    __syncthreads();
    #pragma unroll
    for (int tn = 0; tn < 4; ++tn)
        #pragma unroll
        for (int kk = 0; kk < 2; ++kk)
            whhf[tn][kk] = *(const s16x8*)&s_stage[(tn*16 + lm) * STR + kk*32 + q*8];

    // ---- resident Win^T (unpermuted K = x features), slots k<16 ----
    {
        int k = tid >> 4, nn = (tid & 15) * 4;
        const float* src = Win + k * HIDN + nn;
        #pragma unroll
        for (int i = 0; i < 4; ++i) s_win[(nn + i) * SW + k] = f2bf(src[i]);
    }
    // ---- resident biases / Wout ----
    if (tid < HIDN) {
        s_bin[tid]  = bin_g[tid];
        s_bh[tid]   = bh_g[tid] * SCALE;
        s_wout[tid] = Wout[tid];
    }
    const float boutf = bout_g[0];
    __syncthreads();   // all resident LDS ready; staging dead

    for (int ti = 0; ti < nti; ++ti) {
        const int tt = tt0 + ti;
        u32x4 hpv[2];   // packed h = next step's B-frags

        #pragma unroll
        for (int d = 0; d < DLAG; ++d) {
            // ---- u = relu(Win^T x + b_in), packed to B-frag via pi ----
            s16x8 xf = {0,0,0,0,0,0,0,0};
            if (q < 2) {   // features k = q*8+j < 16; lanes q>=2 supply zeros
                const float* px = x + ((size_t)(tt + d) * NG + myg) * NXF + q*8;
                f32x4 a = *(const f32x4*)px;
                f32x4 b = *(const f32x4*)(px + 4);
                u32x4 xi;
                xi[0] = pk2bf(a[0], a[1]);
                xi[1] = pk2bf(a[2], a[3]);
                xi[2] = pk2bf(b[0], b[1]);
                xi[3] = pk2bf(b[2], b[3]);
                xf = __builtin_bit_cast(s16x8, xi);
            }
            u32x4 upk[2];
            #pragma unroll
            for (int tj = 0; tj < 4; ++tj) {
                s16x8 wf = *(const s16x8*)&s_win[(tj*16 + lm) * SW + q*8];
                f32x4 c  = *(const f32x4*)&s_bin[tj*16 + q*4];
                f32x4 ua = __builtin_amdgcn_mfma_f32_16x16x32_bf16(wf, xf, c, 0, 0, 0);
                upk[tj>>1][(tj&1)*2+0] = pk2bf(fmaxf(ua[0],0.f), fmaxf(ua[1],0.f));
                upk[tj>>1][(tj&1)*2+1] = pk2bf(fmaxf(ua[2],0.f), fmaxf(ua[3],0.f));
            }

            // ---- h = tanh'(Wxh'.u + Whh'.h + bh') ----
            f32x4 ha[4];
            #pragma unroll
            for (int tn = 0; tn < 4; ++tn)
                ha[tn] = *(const f32x4*)&s_bh[tn*16 + q*4];
            #pragma unroll
            for (int kk = 0; kk < 2; ++kk) {
                s16x8 uf = __builtin_bit_cast(s16x8, upk[kk]);
                #pragma unroll
                for (int tn = 0; tn < 4; ++tn)
                    ha[tn] = __builtin_amdgcn_mfma_f32_16x16x32_bf16(
                        wxhf[tn][kk], uf, ha[tn], 0, 0, 0);
            }
            if (d > 0) {
                #pragma unroll
                for (int kk = 0; kk < 2; ++kk) {
                    s16x8 hf = __builtin_bit_cast(s16x8, hpv[kk]);
                    #pragma unroll
                    for (int tn = 0; tn < 4; ++tn)
                        ha[tn] = __builtin_amdgcn_mfma_f32_16x16x32_bf16(
                            whhf[tn][kk], hf, ha[tn], 0, 0, 0);
                }
            }
            float tv[4][4];
            #pragma unroll
            for (int tn = 0; tn < 4; ++tn)
                #pragma unroll
                for (int r = 0; r < 4; ++r)
                    tv[tn][r] = tanh_pre(ha[tn][r]);

            if (d < DLAG - 1) {
                #pragma unroll
                for (int tn = 0; tn < 4; ++tn) {
                    hpv[tn>>1][(tn&1)*2+0] = pk2bf(tv[tn][0], tv[tn][1]);
                    hpv[tn>>1][(tn&1)*2+1] = pk2bf(tv[tn][2], tv[tn][3]);
                }
            } else {
                // epilogue: y = Wout.h + bout (lane holds units 16tn+4q+r)
                float acc = 0.f;
                #pragma unroll
                for (int tn = 0; tn < 4; ++tn) {
                    f32x4 wo = *(const f32x4*)&s_wout[tn*16 + q*4];
                    #pragma unroll
                    for (int r = 0; r < 4; ++r) acc += tv[tn][r] * wo[r];
                }
                acc += __shfl_xor(acc, 16, 64);
                acc += __shfl_xor(acc, 32, 64);
                if (lane < 16)
                    out[(size_t)(tt + DLAG) * NG + G0 + wrow0 + lane] = acc + boutf;
            }
        }
    }
}

extern "C" void kernel_launch(void* const* d_in, const int* in_sizes, int n_in,
                              void* d_out, int out_size, void* d_ws, size_t ws_size,
                              hipStream_t stream) {
    const float* x    = (const float*)d_in[0];
    const float* Win  = (const float*)d_in[1];
    const float* bin  = (const float*)d_in[2];
    const float* Wxh  = (const float*)d_in[3];
    const float* Whh  = (const float*)d_in[4];
    const float* bh   = (const float*)d_in[5];
    const float* Wout = (const float*)d_in[6];
    const float* bout = (const float*)d_in[7];
    float* out = (float*)d_out;

    dim3 grid(NG / GBLK, (TOUTN + TTB - 1) / TTB);  // (32, 64)
    narx_kernel<<<grid, dim3(256), 0, stream>>>(x, Win, bin, Wxh, Whh, bh, Wout, bout, out);
}